// Round 4
// baseline (3459.986 us; speedup 1.0000x reference)
//
#include <hip/hip_runtime.h>
#include <hip/hip_cooperative_groups.h>
#include <math.h>

namespace cg = cooperative_groups;

#define I_SZ   4096
#define H_SZ   3584
#define O_SZ   512
#define TOTAL  8192
#define HO     4096   // TOTAL - I_SZ (rows that actually update)
#define BETA   0.1f
#define LR     0.5f
#define T1C    20
#define T2C    4

#define NBLK   512    // cooperative grid: 2 blocks/CU on 256 CUs
#define NTHR   512    // 8 waves
#define RPB    8      // rows per block (NBLK*RPB == HO)

// ---------------- init: state buffers ----------------
__global__ void k_init(const float* __restrict__ x, float* __restrict__ s_a,
                       float* __restrict__ s_b) {
    int i = blockIdx.x * 256 + threadIdx.x;
    if (i < I_SZ) { float v = x[i]; s_a[i] = v; s_b[i] = v; }
    else if (i < TOTAL) { s_a[i] = 0.0f; }
}

// ---------------- te[t] = mask*target; tsum = sum(te) ----------------
__global__ void k_prep(const float* __restrict__ target, const float* __restrict__ mask,
                       float* __restrict__ te, float* __restrict__ tsum) {
    __shared__ float red[8];
    int t = threadIdx.x;  // 512
    float v = mask[t] * target[t];
    te[t] = v;
    float z = v;
    for (int off = 32; off > 0; off >>= 1) z += __shfl_down(z, off, 64);
    if ((t & 63) == 0) red[t >> 6] = z;
    __syncthreads();
    if (t == 0) { float s = 0.f; for (int i = 0; i < 8; i++) s += red[i]; tsum[0] = s; }
}

// ---------------- build Wt = sym(W) lower-right block, 0.5 baked in ----------------
__global__ void k_build_wt(const float* __restrict__ W, float* __restrict__ Wt) {
    __shared__ float tb[32][33];
    int c0 = blockIdx.x * 32;
    int r0 = blockIdx.y * 32;
    int tx = threadIdx.x;   // 0..31
    int ty = threadIdx.y;   // 0..7
    #pragma unroll
    for (int k = 0; k < 4; k++) {
        int a = ty + 8 * k;
        tb[a][tx] = W[(size_t)(I_SZ + c0 + a) * TOTAL + (I_SZ + r0 + tx)];
    }
    __syncthreads();
    #pragma unroll
    for (int k = 0; k < 4; k++) {
        int ri = ty + 8 * k;
        int r = r0 + ri, c = c0 + tx;
        float direct = W[(size_t)(I_SZ + r) * TOTAL + (I_SZ + c)];
        Wt[(size_t)r * HO + c] = 0.5f * (direct + tb[tx][ri]);
    }
}

// ---------------- bvec[r] = 0.5 * W[I_SZ+r][0:I_SZ] . x (store) ----------------
__global__ void k_build_b1(const float* __restrict__ W, const float* __restrict__ x,
                           float* __restrict__ bvec) {
    int r = blockIdx.x;
    int t = threadIdx.x;
    const float4* wrow = (const float4*)(W + (size_t)(I_SZ + r) * TOTAL);
    const float4* xv   = (const float4*)x;
    float acc = 0.0f;
    #pragma unroll
    for (int k = 0; k < 4; k++) {
        int idx = t + 256 * k;       // < 1024
        float4 w  = wrow[idx];
        float4 s4 = xv[idx];
        acc += w.x * s4.x + w.y * s4.y + w.z * s4.z + w.w * s4.w;
    }
    __shared__ float red[4];
    for (int off = 32; off > 0; off >>= 1) acc += __shfl_down(acc, off, 64);
    if ((t & 63) == 0) red[t >> 6] = acc;
    __syncthreads();
    if (t == 0) bvec[r] = 0.5f * (red[0] + red[1] + red[2] + red[3]);
}

// ---------------- bvec[c] += 0.5 * sum_j W[j][I_SZ+c]*x[j] (atomic, after b1) --------
__global__ void k_build_b2(const float* __restrict__ W, const float* __restrict__ x,
                           float* __restrict__ bvec) {
    int c  = blockIdx.x * 256 + threadIdx.x;   // 0..HO-1
    int j0 = blockIdx.y * 64;
    float acc = 0.0f;
    for (int j = j0; j < j0 + 64; j++)
        acc += W[(size_t)j * TOTAL + (I_SZ + c)] * x[j];
    atomicAdd(&bvec[c], 0.5f * acc);
}

// ---------------- persistent cooperative kernel: all 24 steps ----------------
__global__ void __launch_bounds__(NTHR, 4) k_run(
    const float* __restrict__ Wt, const float* __restrict__ bvec,
    const float* __restrict__ te, const float* __restrict__ tsum,
    float* __restrict__ s_a, float* __restrict__ s_b)
{
    cg::grid_group grid = cg::this_grid();
    const int blk  = blockIdx.x;
    const int tid  = threadIdx.x;
    const int wave = tid >> 6;
    const int lane = tid & 63;
    const int row  = blk * RPB + wave;        // 0..HO-1
    const float4* w4 = (const float4*)(Wt + (size_t)row * HO);
    const float   ts = tsum[0];
    const bool out_block = (blk >= H_SZ / RPB);   // blocks owning rows >= H_SZ

    __shared__ float red[8];
    __shared__ float sm_m, sm_z;

    for (int it = 0; it < T1C + T2C; ++it) {
        const float* cur = (it & 1) ? s_b : s_a;
        float*       nxt = (it & 1) ? s_a : s_b;
        const bool betap = (it >= T1C);

        if (betap && out_block) {
            // block-redundant softmax stats over the 512 logits
            float l = cur[I_SZ + H_SZ + tid];
            float m = l;
            for (int off = 32; off > 0; off >>= 1) m = fmaxf(m, __shfl_down(m, off, 64));
            if (lane == 0) red[wave] = m;
            __syncthreads();
            if (tid == 0) { float v = red[0]; for (int i = 1; i < 8; i++) v = fmaxf(v, red[i]); sm_m = v; }
            __syncthreads();
            float z = expf(l - sm_m);
            for (int off = 32; off > 0; off >>= 1) z += __shfl_down(z, off, 64);
            if (lane == 0) red[wave] = z;
            __syncthreads();
            if (tid == 0) { float v = 0.f; for (int i = 0; i < 8; i++) v += red[i]; sm_z = v; }
            __syncthreads();
        }

        // one wave per row: 4096-wide dot (Wt has the 0.5 baked in)
        const float4* s4 = (const float4*)(cur + I_SZ);
        float acc = 0.0f;
        #pragma unroll 8
        for (int k = 0; k < 16; ++k) {
            float4 w = w4[lane + 64 * k];
            float4 s = s4[lane + 64 * k];
            acc += w.x * s.x + w.y * s.y + w.z * s.z + w.w * s.w;
        }
        for (int off = 32; off > 0; off >>= 1) acc += __shfl_down(acc, off, 64);
        if (lane == 0) {
            float g = acc + bvec[row];
            if (betap && row >= H_SZ) {
                int j = row - H_SZ;
                float p = expf(cur[I_SZ + H_SZ + j] - sm_m) / sm_z;
                g += -BETA * (p * ts - te[j]);
            }
            int i = I_SZ + row;
            nxt[i] = tanhf(cur[i] - LR * g);
        }
        __threadfence();
        grid.sync();
    }
}

// ---------------- fallback per-step kernel (bvec + inline softmax) ----------------
template <bool BETA_STEP>
__global__ void k_step3(const float* __restrict__ Wt, const float* __restrict__ bvec,
                        const float* __restrict__ s_cur, float* __restrict__ s_next,
                        const float* __restrict__ te, const float* __restrict__ tsum) {
    int r = blockIdx.x;
    int t = threadIdx.x;
    __shared__ float red[4];
    __shared__ float sm_m, sm_z;

    if (BETA_STEP && r >= H_SZ) {
        float l0 = s_cur[I_SZ + H_SZ + t];
        float l1 = s_cur[I_SZ + H_SZ + t + 256];
        float m = fmaxf(l0, l1);
        for (int off = 32; off > 0; off >>= 1) m = fmaxf(m, __shfl_down(m, off, 64));
        if ((t & 63) == 0) red[t >> 6] = m;
        __syncthreads();
        if (t == 0) sm_m = fmaxf(fmaxf(red[0], red[1]), fmaxf(red[2], red[3]));
        __syncthreads();
        float z = expf(l0 - sm_m) + expf(l1 - sm_m);
        for (int off = 32; off > 0; off >>= 1) z += __shfl_down(z, off, 64);
        if ((t & 63) == 0) red[t >> 6] = z;
        __syncthreads();
        if (t == 0) sm_z = red[0] + red[1] + red[2] + red[3];
        __syncthreads();
    }

    const float4* wrow = (const float4*)(Wt + (size_t)r * HO);
    const float4* sv   = (const float4*)(s_cur + I_SZ);
    float acc = 0.0f;
    #pragma unroll
    for (int k = 0; k < 4; k++) {
        int idx = t + 256 * k;
        float4 w  = wrow[idx];
        float4 s4 = sv[idx];
        acc += w.x * s4.x + w.y * s4.y + w.z * s4.z + w.w * s4.w;
    }
    for (int off = 32; off > 0; off >>= 1) acc += __shfl_down(acc, off, 64);
    __syncthreads();
    if ((t & 63) == 0) red[t >> 6] = acc;
    __syncthreads();
    if (t == 0) {
        float g = bvec[r] + red[0] + red[1] + red[2] + red[3];
        if (BETA_STEP && r >= H_SZ) {
            int j = r - H_SZ;
            float p = expf(s_cur[I_SZ + H_SZ + j] - sm_m) / sm_z;
            g += -BETA * (p * tsum[0] - te[j]);
        }
        int i = I_SZ + r;
        s_next[i] = tanhf(s_cur[i] - LR * g);
    }
}

extern "C" void kernel_launch(void* const* d_in, const int* in_sizes, int n_in,
                              void* d_out, int out_size, void* d_ws, size_t ws_size,
                              hipStream_t stream) {
    const float* W      = (const float*)d_in[0];
    const float* x      = (const float*)d_in[1];
    const float* target = (const float*)d_in[2];
    const float* mask   = (const float*)d_in[3];
    float* out = (float*)d_out;   // state buffer A (final state lands here: 24 steps even)
    char*  ws  = (char*)d_ws;

    const size_t WS_WT = (size_t)HO * HO * sizeof(float);   // 64 MB
    float* Wt   = (float*)ws;
    float* bvec = (float*)(ws + WS_WT);
    float* te   = bvec + HO;
    float* tsum = te + O_SZ;
    float* s_b  = tsum + 64;   // aligned-ish scratch state buffer B

    k_init<<<(TOTAL + 255) / 256, 256, 0, stream>>>(x, out, s_b);
    k_prep<<<1, 512, 0, stream>>>(target, mask, te, tsum);
    k_build_wt<<<dim3(HO / 32, HO / 32), dim3(32, 8), 0, stream>>>(W, Wt);
    k_build_b1<<<HO, 256, 0, stream>>>(W, x, bvec);
    k_build_b2<<<dim3(HO / 256, I_SZ / 64), 256, 0, stream>>>(W, x, bvec);

    void* args[] = { (void*)&Wt, (void*)&bvec, (void*)&te, (void*)&tsum,
                     (void*)&out, (void*)&s_b };
    hipError_t err = hipLaunchCooperativeKernel((const void*)k_run, dim3(NBLK), dim3(NTHR),
                                                args, 0, stream);
    if (err != hipSuccess) {
        // fallback: per-step dispatch chain (R3 structure, same math)
        const float* cur = out;
        float* nxt = s_b;
        for (int it = 0; it < T1C + T2C; it++) {
            if (it >= T1C) {
                k_step3<true><<<HO, 256, 0, stream>>>(Wt, bvec, cur, nxt, te, tsum);
            } else {
                k_step3<false><<<HO, 256, 0, stream>>>(Wt, bvec, cur, nxt, te, tsum);
            }
            float* tmp = (float*)cur; cur = nxt; nxt = tmp;
        }
    }
}

// Round 5
// 653.802 us; speedup vs baseline: 5.2921x; 5.2921x over previous
//
#include <hip/hip_runtime.h>
#include <math.h>

#define I_SZ   4096
#define H_SZ   3584
#define O_SZ   512
#define TOTAL  8192
#define HO     4096   // TOTAL - I_SZ (rows that actually update)
#define BETA   0.1f
#define LR     0.5f
#define T1C    20
#define T2C    4

// ---------------- init: state buffers ----------------
__global__ void k_init(const float* __restrict__ x, float* __restrict__ s_a,
                       float* __restrict__ s_b) {
    int i = blockIdx.x * 256 + threadIdx.x;
    if (i < I_SZ) { float v = x[i]; s_a[i] = v; s_b[i] = v; }
    else if (i < TOTAL) { s_a[i] = 0.0f; }
}

// ---------------- te[t] = mask*target; tsum = sum(te) ----------------
__global__ void k_prep(const float* __restrict__ target, const float* __restrict__ mask,
                       float* __restrict__ te, float* __restrict__ tsum) {
    __shared__ float red[8];
    int t = threadIdx.x;  // 512
    float v = mask[t] * target[t];
    te[t] = v;
    float z = v;
    for (int off = 32; off > 0; off >>= 1) z += __shfl_down(z, off, 64);
    if ((t & 63) == 0) red[t >> 6] = z;
    __syncthreads();
    if (t == 0) { float s = 0.f; for (int i = 0; i < 8; i++) s += red[i]; tsum[0] = s; }
}

// ---------------- build Wt = sym(W) lower-right block, 0.5 baked in ----------------
__global__ void k_build_wt(const float* __restrict__ W, float* __restrict__ Wt) {
    __shared__ float tb[32][33];
    int c0 = blockIdx.x * 32;
    int r0 = blockIdx.y * 32;
    int tx = threadIdx.x;   // 0..31
    int ty = threadIdx.y;   // 0..7
    #pragma unroll
    for (int k = 0; k < 4; k++) {
        int a = ty + 8 * k;
        tb[a][tx] = W[(size_t)(I_SZ + c0 + a) * TOTAL + (I_SZ + r0 + tx)];
    }
    __syncthreads();
    #pragma unroll
    for (int k = 0; k < 4; k++) {
        int ri = ty + 8 * k;
        int r = r0 + ri, c = c0 + tx;
        float direct = W[(size_t)(I_SZ + r) * TOTAL + (I_SZ + c)];
        Wt[(size_t)r * HO + c] = 0.5f * (direct + tb[tx][ri]);
    }
}

// ---------------- bvec[r] = 0.5 * W[I_SZ+r][0:I_SZ] . x (store) ----------------
__global__ void k_build_b1(const float* __restrict__ W, const float* __restrict__ x,
                           float* __restrict__ bvec) {
    int r = blockIdx.x;
    int t = threadIdx.x;
    const float4* wrow = (const float4*)(W + (size_t)(I_SZ + r) * TOTAL);
    const float4* xv   = (const float4*)x;
    float acc = 0.0f;
    #pragma unroll
    for (int k = 0; k < 4; k++) {
        int idx = t + 256 * k;       // < 1024
        float4 w  = wrow[idx];
        float4 s4 = xv[idx];
        acc += w.x * s4.x + w.y * s4.y + w.z * s4.z + w.w * s4.w;
    }
    __shared__ float red[4];
    for (int off = 32; off > 0; off >>= 1) acc += __shfl_down(acc, off, 64);
    if ((t & 63) == 0) red[t >> 6] = acc;
    __syncthreads();
    if (t == 0) bvec[r] = 0.5f * (red[0] + red[1] + red[2] + red[3]);
}

// ---------------- bvec[c] += 0.5 * sum_j W[j][I_SZ+c]*x[j] (atomic, after b1) --------
__global__ void k_build_b2(const float* __restrict__ W, const float* __restrict__ x,
                           float* __restrict__ bvec) {
    int c  = blockIdx.x * 256 + threadIdx.x;   // 0..HO-1
    int j0 = blockIdx.y * 64;
    float acc = 0.0f;
    for (int j = j0; j < j0 + 64; j++)
        acc += W[(size_t)j * TOTAL + (I_SZ + c)] * x[j];
    atomicAdd(&bvec[c], 0.5f * acc);
}

// ---------------- per-step kernel: wave-per-row, deep MLP ----------------
// grid 1024 x 256 threads (4 waves = 4 rows/block). No __syncthreads in hot path.
template <bool BETA_STEP>
__global__ void __launch_bounds__(256, 4) k_step4(
    const float* __restrict__ Wt, const float* __restrict__ bvec,
    const float* __restrict__ s_cur, float* __restrict__ s_next,
    const float* __restrict__ te, const float* __restrict__ tsum)
{
    const int blk  = blockIdx.x;
    const int t    = threadIdx.x;
    const int wave = t >> 6;
    const int lane = t & 63;
    const int row  = blk * 4 + wave;

    __shared__ float red[4];
    __shared__ float sm_m, sm_z;

    if (BETA_STEP && blk >= H_SZ / 4) {
        // block-redundant softmax stats over the 512 logits (output-row blocks only)
        float l0 = s_cur[I_SZ + H_SZ + t];
        float l1 = s_cur[I_SZ + H_SZ + t + 256];
        float m = fmaxf(l0, l1);
        for (int off = 32; off > 0; off >>= 1) m = fmaxf(m, __shfl_down(m, off, 64));
        if (lane == 0) red[wave] = m;
        __syncthreads();
        if (t == 0) sm_m = fmaxf(fmaxf(red[0], red[1]), fmaxf(red[2], red[3]));
        __syncthreads();
        float z = expf(l0 - sm_m) + expf(l1 - sm_m);
        for (int off = 32; off > 0; off >>= 1) z += __shfl_down(z, off, 64);
        if (lane == 0) red[wave] = z;
        __syncthreads();
        if (t == 0) sm_z = red[0] + red[1] + red[2] + red[3];
        __syncthreads();
    }

    // 4096-wide dot: explicit 16-deep register buffer of the row -> 16 loads in flight
    const float4* w4 = (const float4*)(Wt + (size_t)row * HO);
    const float4* s4 = (const float4*)(s_cur + I_SZ);
    float4 w[16];
    #pragma unroll
    for (int k = 0; k < 16; k++) w[k] = w4[lane + 64 * k];
    float acc = 0.0f;
    #pragma unroll
    for (int k = 0; k < 16; k++) {
        float4 s = s4[lane + 64 * k];
        acc += w[k].x * s.x + w[k].y * s.y + w[k].z * s.z + w[k].w * s.w;
    }
    for (int off = 32; off > 0; off >>= 1) acc += __shfl_down(acc, off, 64);
    if (lane == 0) {
        float g = acc + bvec[row];
        if (BETA_STEP && row >= H_SZ) {
            int j = row - H_SZ;
            float p = expf(s_cur[I_SZ + H_SZ + j] - sm_m) / sm_z;
            g += -BETA * (p * tsum[0] - te[j]);
        }
        int i = I_SZ + row;
        s_next[i] = tanhf(s_cur[i] - LR * g);
    }
}

// ---------------- fallback path (small ws): fp32 two-pass on raw W ----------------
__global__ void k_softmax(const float* __restrict__ s_cur,
                          const float* __restrict__ target,
                          const float* __restrict__ mask,
                          float* __restrict__ corr) {
    __shared__ float buf[8];
    __shared__ float s_m, s_z, s_ts;
    int t = threadIdx.x;  // 512 threads
    float logit = s_cur[I_SZ + H_SZ + t];
    float tev = mask[t] * target[t];
    float m = logit;
    for (int off = 32; off > 0; off >>= 1) m = fmaxf(m, __shfl_down(m, off, 64));
    if ((t & 63) == 0) buf[t >> 6] = m;
    __syncthreads();
    if (t == 0) { float v = buf[0]; for (int i = 1; i < 8; i++) v = fmaxf(v, buf[i]); s_m = v; }
    __syncthreads();
    float e = expf(logit - s_m);
    float z = e;
    for (int off = 32; off > 0; off >>= 1) z += __shfl_down(z, off, 64);
    if ((t & 63) == 0) buf[t >> 6] = z;
    __syncthreads();
    if (t == 0) { float v = 0.f; for (int i = 0; i < 8; i++) v += buf[i]; s_z = v; }
    __syncthreads();
    float ts = tev;
    for (int off = 32; off > 0; off >>= 1) ts += __shfl_down(ts, off, 64);
    if ((t & 63) == 0) buf[t >> 6] = ts;
    __syncthreads();
    if (t == 0) { float v = 0.f; for (int i = 0; i < 8; i++) v += buf[i]; s_ts = v; }
    __syncthreads();
    float p = e / s_z;
    corr[t] = -BETA * (p * s_ts - tev);
}

__global__ void k_rowmv(const float* __restrict__ W, const float* __restrict__ s_cur,
                        float* __restrict__ g_row) {
    int r = blockIdx.x;
    int t = threadIdx.x;
    const float4* wrow = (const float4*)(W + (size_t)(I_SZ + r) * TOTAL);
    const float4* sv   = (const float4*)s_cur;
    float acc = 0.0f;
    #pragma unroll
    for (int k = 0; k < 8; k++) {
        float4 w  = wrow[t + 256 * k];
        float4 s4 = sv[t + 256 * k];
        acc += w.x * s4.x + w.y * s4.y + w.z * s4.z + w.w * s4.w;
    }
    __shared__ float red[4];
    for (int off = 32; off > 0; off >>= 1) acc += __shfl_down(acc, off, 64);
    if ((t & 63) == 0) red[t >> 6] = acc;
    __syncthreads();
    if (t == 0) g_row[r] = red[0] + red[1] + red[2] + red[3];
}

__global__ void k_colmv(const float* __restrict__ W, const float* __restrict__ s_cur,
                        float* __restrict__ g_col) {
    int cl = blockIdx.x * 256 + threadIdx.x;
    int c  = I_SZ + cl;
    int r0 = blockIdx.y * 256;
    float acc = 0.0f;
    for (int r = r0; r < r0 + 256; r++)
        acc += W[(size_t)r * TOTAL + c] * s_cur[r];
    atomicAdd(&g_col[cl], acc);
}

template <bool WITH_CORR>
__global__ void k_update(const float* __restrict__ g_row, const float* __restrict__ g_col,
                         const float* __restrict__ s_cur, float* __restrict__ s_next,
                         const float* __restrict__ corr) {
    int r = blockIdx.x * 256 + threadIdx.x;
    if (r >= HO) return;
    float g = 0.5f * (g_row[r] + g_col[r]);
    if (WITH_CORR && r >= H_SZ) g += corr[r - H_SZ];
    int i = I_SZ + r;
    s_next[i] = tanhf(s_cur[i] - LR * g);
}

__global__ void k_zero(float* __restrict__ p, int n) {
    int i = blockIdx.x * 256 + threadIdx.x;
    if (i < n) p[i] = 0.0f;
}

extern "C" void kernel_launch(void* const* d_in, const int* in_sizes, int n_in,
                              void* d_out, int out_size, void* d_ws, size_t ws_size,
                              hipStream_t stream) {
    const float* W      = (const float*)d_in[0];
    const float* x      = (const float*)d_in[1];
    const float* target = (const float*)d_in[2];
    const float* mask   = (const float*)d_in[3];
    float* out = (float*)d_out;   // state buffer A (24 steps even -> final lands here)
    char*  ws  = (char*)d_ws;

    const size_t WS_WT = (size_t)HO * HO * sizeof(float);   // 64 MB
    const size_t ws_need = WS_WT + 256 * 1024;
    const bool fast = (ws_size >= ws_need);
    const int  STEPS = T1C + T2C;  // 24

    if (fast) {
        float* Wt   = (float*)ws;
        float* bvec = (float*)(ws + WS_WT);
        float* te   = bvec + HO;
        float* tsum = te + O_SZ;
        float* s_b  = tsum + 64;

        k_init<<<(TOTAL + 255) / 256, 256, 0, stream>>>(x, out, s_b);
        k_prep<<<1, 512, 0, stream>>>(target, mask, te, tsum);
        k_build_wt<<<dim3(HO / 32, HO / 32), dim3(32, 8), 0, stream>>>(W, Wt);
        k_build_b1<<<HO, 256, 0, stream>>>(W, x, bvec);
        k_build_b2<<<dim3(HO / 256, I_SZ / 64), 256, 0, stream>>>(W, x, bvec);

        const float* cur = out;
        float* nxt = s_b;
        for (int it = 0; it < STEPS; it++) {
            if (it >= T1C) {
                k_step4<true><<<HO / 4, 256, 0, stream>>>(Wt, bvec, cur, nxt, te, tsum);
            } else {
                k_step4<false><<<HO / 4, 256, 0, stream>>>(Wt, bvec, cur, nxt, te, tsum);
            }
            float* tmp = (float*)cur; cur = nxt; nxt = tmp;
        }
    } else {
        float* s_b   = (float*)ws;
        float* corr  = s_b + TOTAL;
        float* g_row = corr + O_SZ;
        float* g_col = g_row + HO;

        k_init<<<(TOTAL + 255) / 256, 256, 0, stream>>>(x, out, s_b);

        const float* cur = out;
        float* nxt = s_b;
        for (int it = 0; it < STEPS; it++) {
            bool wc = (it >= T1C);
            k_zero<<<(HO + 255) / 256, 256, 0, stream>>>(g_col, HO);
            k_rowmv<<<HO, 256, 0, stream>>>(W, cur, g_row);
            k_colmv<<<dim3(HO / 256, TOTAL / 256), 256, 0, stream>>>(W, cur, g_col);
            if (wc) {
                k_softmax<<<1, 512, 0, stream>>>(cur, target, mask, corr);
                k_update<true><<<HO / 256, 256, 0, stream>>>(g_row, g_col, cur, nxt, corr);
            } else {
                k_update<false><<<HO / 256, 256, 0, stream>>>(g_row, g_col, cur, nxt, corr);
            }
            float* tmp = (float*)cur; cur = nxt; nxt = tmp;
        }
    }
}

// Round 6
// 511.932 us; speedup vs baseline: 6.7587x; 1.2771x over previous
//
#include <hip/hip_runtime.h>
#include <math.h>

#define I_SZ   4096
#define H_SZ   3584
#define O_SZ   512
#define TOTAL  8192
#define HO     4096   // TOTAL - I_SZ (rows that actually update)
#define BETA   0.1f
#define LR     0.5f
#define T1C    20
#define T2C    4

#define NBLK   512    // persistent grid: 2 blocks/CU on 256 CUs
#define NTHR   512    // 8 waves -> 8 rows/block, 1 row/wave
#define NGRP   8      // barrier: 8 groups of 64 arrivals

// ---------------- init: state buffers + zero barrier state ----------------
__global__ void k_init(const float* __restrict__ x, float* __restrict__ s_a,
                       float* __restrict__ s_b, unsigned int* __restrict__ bar) {
    int i = blockIdx.x * 256 + threadIdx.x;
    if (i < I_SZ) { float v = x[i]; s_a[i] = v; s_b[i] = v; }
    else if (i < TOTAL) { s_a[i] = 0.0f; }
    if (i < 1024) bar[i] = 0u;
}

// ---------------- te[t] = mask*target; tsum = sum(te) ----------------
__global__ void k_prep(const float* __restrict__ target, const float* __restrict__ mask,
                       float* __restrict__ te, float* __restrict__ tsum) {
    __shared__ float red[8];
    int t = threadIdx.x;  // 512
    float v = mask[t] * target[t];
    te[t] = v;
    float z = v;
    for (int off = 32; off > 0; off >>= 1) z += __shfl_down(z, off, 64);
    if ((t & 63) == 0) red[t >> 6] = z;
    __syncthreads();
    if (t == 0) { float s = 0.f; for (int i = 0; i < 8; i++) s += red[i]; tsum[0] = s; }
}

// ---------------- build Wt = sym(W) lower-right block, 0.5 baked in ----------------
__global__ void k_build_wt(const float* __restrict__ W, float* __restrict__ Wt) {
    __shared__ float tb[32][33];
    int c0 = blockIdx.x * 32;
    int r0 = blockIdx.y * 32;
    int tx = threadIdx.x;   // 0..31
    int ty = threadIdx.y;   // 0..7
    #pragma unroll
    for (int k = 0; k < 4; k++) {
        int a = ty + 8 * k;
        tb[a][tx] = W[(size_t)(I_SZ + c0 + a) * TOTAL + (I_SZ + r0 + tx)];
    }
    __syncthreads();
    #pragma unroll
    for (int k = 0; k < 4; k++) {
        int ri = ty + 8 * k;
        int r = r0 + ri, c = c0 + tx;
        float direct = W[(size_t)(I_SZ + r) * TOTAL + (I_SZ + c)];
        Wt[(size_t)r * HO + c] = 0.5f * (direct + tb[tx][ri]);
    }
}

// ---------------- bvec[r] = 0.5 * W[I_SZ+r][0:I_SZ] . x (store) ----------------
__global__ void k_build_b1(const float* __restrict__ W, const float* __restrict__ x,
                           float* __restrict__ bvec) {
    int r = blockIdx.x;
    int t = threadIdx.x;
    const float4* wrow = (const float4*)(W + (size_t)(I_SZ + r) * TOTAL);
    const float4* xv   = (const float4*)x;
    float acc = 0.0f;
    #pragma unroll
    for (int k = 0; k < 4; k++) {
        int idx = t + 256 * k;       // < 1024
        float4 w  = wrow[idx];
        float4 s4 = xv[idx];
        acc += w.x * s4.x + w.y * s4.y + w.z * s4.z + w.w * s4.w;
    }
    __shared__ float red[4];
    for (int off = 32; off > 0; off >>= 1) acc += __shfl_down(acc, off, 64);
    if ((t & 63) == 0) red[t >> 6] = acc;
    __syncthreads();
    if (t == 0) bvec[r] = 0.5f * (red[0] + red[1] + red[2] + red[3]);
}

// ---------------- bvec[c] += 0.5 * sum_j W[j][I_SZ+c]*x[j] (atomic, after b1) --------
__global__ void k_build_b2(const float* __restrict__ W, const float* __restrict__ x,
                           float* __restrict__ bvec) {
    int c  = blockIdx.x * 256 + threadIdx.x;   // 0..HO-1
    int j0 = blockIdx.y * 64;
    float acc = 0.0f;
    for (int j = j0; j < j0 + 64; j++)
        acc += W[(size_t)j * TOTAL + (I_SZ + c)] * x[j];
    atomicAdd(&bvec[c], 0.5f * acc);
}

// ---------------- persistent kernel: all 24 steps, hand-rolled barrier ----------------
// bar layout (uints): cnt[g] at bar[g*64] (g=0..7), gcnt at bar[512], flag at bar[576]
__global__ void __launch_bounds__(NTHR, 4) k_run(
    const float* __restrict__ Wt, const float* __restrict__ bvec,
    const float* __restrict__ te, const float* __restrict__ tsum,
    float* __restrict__ s_a, float* __restrict__ s_b,
    unsigned int* __restrict__ bar)
{
    const int blk  = blockIdx.x;
    const int tid  = threadIdx.x;
    const int wave = tid >> 6;
    const int lane = tid & 63;
    const int row  = blk * 8 + wave;          // 0..HO-1
    const float4* w4 = (const float4*)(Wt + (size_t)row * HO);
    const float   ts = tsum[0];
    const float   bv = bvec[row];
    const bool out_block = (blk >= H_SZ / 8); // blocks owning rows >= H_SZ

    __shared__ float sh[HO];                  // staged s_tail (16 KB)
    __shared__ float red[8];
    __shared__ float sm_m, sm_z;

    for (int it = 0; it < T1C + T2C; ++it) {
        const float* cur = (it & 1) ? s_b : s_a;
        float*       nxt = (it & 1) ? s_a : s_b;
        const bool betap = (it >= T1C);

        // ---- stage s_tail -> LDS through the coherence point (agent-scope 8B loads)
        const unsigned long long* cu = (const unsigned long long*)(cur + I_SZ);
        unsigned long long* shu = (unsigned long long*)sh;
        #pragma unroll
        for (int m = 0; m < 4; ++m) {
            int idx = tid + NTHR * m;         // < 2048
            shu[idx] = __hip_atomic_load(&cu[idx], __ATOMIC_RELAXED,
                                         __HIP_MEMORY_SCOPE_AGENT);
        }
        __syncthreads();

        // ---- block-redundant softmax stats (beta phase, output-row blocks only)
        if (betap && out_block) {
            float l = sh[H_SZ + tid];         // logit j=tid
            float m = l;
            for (int off = 32; off > 0; off >>= 1) m = fmaxf(m, __shfl_down(m, off, 64));
            if (lane == 0) red[wave] = m;
            __syncthreads();
            if (tid == 0) { float v = red[0]; for (int i = 1; i < 8; i++) v = fmaxf(v, red[i]); sm_m = v; }
            __syncthreads();
            float z = expf(l - sm_m);
            for (int off = 32; off > 0; off >>= 1) z += __shfl_down(z, off, 64);
            if (lane == 0) red[wave] = z;
            __syncthreads();
            if (tid == 0) { float v = 0.f; for (int i = 0; i < 8; i++) v += red[i]; sm_z = v; }
            __syncthreads();
        }

        // ---- one wave per row: 4096-wide dot, Wt cached (never invalidated), s from LDS
        float4 w[16];
        #pragma unroll
        for (int k = 0; k < 16; ++k) w[k] = w4[lane + 64 * k];
        const float4* sh4 = (const float4*)sh;
        float acc = 0.0f;
        #pragma unroll
        for (int k = 0; k < 16; ++k) {
            float4 s = sh4[lane + 64 * k];
            acc += w[k].x * s.x + w[k].y * s.y + w[k].z * s.z + w[k].w * s.w;
        }
        for (int off = 32; off > 0; off >>= 1) acc += __shfl_down(acc, off, 64);
        if (lane == 0) {
            float g = acc + bv;
            if (betap && row >= H_SZ) {
                float p = expf(sh[row] - sm_m) / sm_z;   // sh[row] == logit of this row
                g += -BETA * (p * ts - te[row - H_SZ]);
            }
            float nv = tanhf(sh[row] - LR * g);          // sh[row] == s_cur[I_SZ+row]
            __hip_atomic_store(&nxt[I_SZ + row], nv, __ATOMIC_RELAXED,
                               __HIP_MEMORY_SCOPE_AGENT);
        }
        __syncthreads();   // drains vmcnt: all agent stores complete at coherence point

        // ---- hierarchical monotone barrier (relaxed agent atomics, no cache flushes)
        const unsigned int e = (unsigned int)(it + 1);
        if (tid == 0) {
            unsigned int g = (unsigned int)blk >> 6;     // 0..7
            unsigned int v = __hip_atomic_fetch_add(&bar[g * 64], 1u, __ATOMIC_RELAXED,
                                                    __HIP_MEMORY_SCOPE_AGENT);
            if (v == e * 64u - 1u) {
                unsigned int v2 = __hip_atomic_fetch_add(&bar[512], 1u, __ATOMIC_RELAXED,
                                                         __HIP_MEMORY_SCOPE_AGENT);
                if (v2 == e * (unsigned int)NGRP - 1u)
                    __hip_atomic_store(&bar[576], e, __ATOMIC_RELAXED,
                                       __HIP_MEMORY_SCOPE_AGENT);
            }
            while (__hip_atomic_load(&bar[576], __ATOMIC_RELAXED,
                                     __HIP_MEMORY_SCOPE_AGENT) < e)
                __builtin_amdgcn_s_sleep(1);
        }
        __syncthreads();
    }
}

// ---------------- fallback per-step kernel (R5 structure) ----------------
template <bool BETA_STEP>
__global__ void __launch_bounds__(256, 4) k_step4(
    const float* __restrict__ Wt, const float* __restrict__ bvec,
    const float* __restrict__ s_cur, float* __restrict__ s_next,
    const float* __restrict__ te, const float* __restrict__ tsum)
{
    const int blk  = blockIdx.x;
    const int t    = threadIdx.x;
    const int wave = t >> 6;
    const int lane = t & 63;
    const int row  = blk * 4 + wave;

    __shared__ float red[4];
    __shared__ float sm_m, sm_z;

    if (BETA_STEP && blk >= H_SZ / 4) {
        float l0 = s_cur[I_SZ + H_SZ + t];
        float l1 = s_cur[I_SZ + H_SZ + t + 256];
        float m = fmaxf(l0, l1);
        for (int off = 32; off > 0; off >>= 1) m = fmaxf(m, __shfl_down(m, off, 64));
        if (lane == 0) red[wave] = m;
        __syncthreads();
        if (t == 0) sm_m = fmaxf(fmaxf(red[0], red[1]), fmaxf(red[2], red[3]));
        __syncthreads();
        float z = expf(l0 - sm_m) + expf(l1 - sm_m);
        for (int off = 32; off > 0; off >>= 1) z += __shfl_down(z, off, 64);
        if (lane == 0) red[wave] = z;
        __syncthreads();
        if (t == 0) sm_z = red[0] + red[1] + red[2] + red[3];
        __syncthreads();
    }

    const float4* w4 = (const float4*)(Wt + (size_t)row * HO);
    const float4* s4 = (const float4*)(s_cur + I_SZ);
    float4 w[16];
    #pragma unroll
    for (int k = 0; k < 16; k++) w[k] = w4[lane + 64 * k];
    float acc = 0.0f;
    #pragma unroll
    for (int k = 0; k < 16; k++) {
        float4 s = s4[lane + 64 * k];
        acc += w[k].x * s.x + w[k].y * s.y + w[k].z * s.z + w[k].w * s.w;
    }
    for (int off = 32; off > 0; off >>= 1) acc += __shfl_down(acc, off, 64);
    if (lane == 0) {
        float g = acc + bvec[row];
        if (BETA_STEP && row >= H_SZ) {
            int j = row - H_SZ;
            float p = expf(s_cur[I_SZ + H_SZ + j] - sm_m) / sm_z;
            g += -BETA * (p * tsum[0] - te[j]);
        }
        int i = I_SZ + row;
        s_next[i] = tanhf(s_cur[i] - LR * g);
    }
}

extern "C" void kernel_launch(void* const* d_in, const int* in_sizes, int n_in,
                              void* d_out, int out_size, void* d_ws, size_t ws_size,
                              hipStream_t stream) {
    const float* W      = (const float*)d_in[0];
    const float* x      = (const float*)d_in[1];
    const float* target = (const float*)d_in[2];
    const float* mask   = (const float*)d_in[3];
    float* out = (float*)d_out;   // state buffer A (24 steps even -> final lands here)
    char*  ws  = (char*)d_ws;

    const size_t WS_WT = (size_t)HO * HO * sizeof(float);   // 64 MB
    float*        Wt   = (float*)ws;
    float*        bvec = (float*)(ws + WS_WT);
    float*        te   = bvec + HO;
    float*        tsum = te + O_SZ;
    float*        s_b  = tsum + 64;
    unsigned int* bar  = (unsigned int*)(s_b + TOTAL + 64);

    k_init<<<(TOTAL + 255) / 256, 256, 0, stream>>>(x, out, s_b, bar);
    k_prep<<<1, 512, 0, stream>>>(target, mask, te, tsum);
    k_build_wt<<<dim3(HO / 32, HO / 32), dim3(32, 8), 0, stream>>>(W, Wt);
    k_build_b1<<<HO, 256, 0, stream>>>(W, x, bvec);
    k_build_b2<<<dim3(HO / 256, I_SZ / 64), 256, 0, stream>>>(W, x, bvec);

    void* args[] = { (void*)&Wt, (void*)&bvec, (void*)&te, (void*)&tsum,
                     (void*)&out, (void*)&s_b, (void*)&bar };
    hipError_t err = hipLaunchCooperativeKernel((const void*)k_run, dim3(NBLK), dim3(NTHR),
                                                args, 0, stream);
    if (err != hipSuccess) {
        // fallback: 24-dispatch chain (R5 structure, known-good 654 us)
        const float* cur = out;
        float* nxt = s_b;
        for (int it = 0; it < T1C + T2C; it++) {
            if (it >= T1C) {
                k_step4<true><<<HO / 4, 256, 0, stream>>>(Wt, bvec, cur, nxt, te, tsum);
            } else {
                k_step4<false><<<HO / 4, 256, 0, stream>>>(Wt, bvec, cur, nxt, te, tsum);
            }
            float* tmp = (float*)cur; cur = nxt; nxt = tmp;
        }
    }
}